// Round 5
// baseline (10.862 us; speedup 1.0000x reference)
//
#include <hip/hip_runtime.h>

// EmbeddingOnehot: out[n, :] = weights[idx[n], :]  (one_hot @ W == row gather)
// idx: int32 [16384], weights: f32 [32000, 128], out: f32 [16384, 128]
//
// R4 (resubmit after infra failure): 8 independent gather chains per thread,
// 256 workgroups (1 per CU) to minimize dispatch ramp. In-flight bytes/CU
// invariant (~32 KB) regardless of config, so this isolates launch/ramp cost.
// Nontemporal stores.

#define N_TOKENS 16384
#define QUADS_PER_ROW 32                       // 128 floats = 32 x 16B
#define TOTAL_QUADS (N_TOKENS * QUADS_PER_ROW) // 524288
#define CHAINS 8
#define NTHREADS (TOTAL_QUADS / CHAINS)        // 65536
#define CHUNK (NTHREADS)                       // quad-index stride per chain

typedef float fvec4 __attribute__((ext_vector_type(4)));

__global__ __launch_bounds__(256) void embedding_gather8_kernel(
    const int* __restrict__ idx,
    const fvec4* __restrict__ w4,
    fvec4* __restrict__ out4)
{
    int j = blockIdx.x * blockDim.x + threadIdx.x;  // 0 .. 65535

    int   p[CHAINS];
    int   r[CHAINS];
    fvec4 v[CHAINS];

#pragma unroll
    for (int k = 0; k < CHAINS; ++k) {
        p[k] = j + k * CHUNK;
        r[k] = idx[p[k] >> 5];     // independent idx loads, L1-broadcast
    }
#pragma unroll
    for (int k = 0; k < CHAINS; ++k) {
        v[k] = w4[r[k] * QUADS_PER_ROW + (p[k] & 31)];  // 8 gathers in flight
    }
#pragma unroll
    for (int k = 0; k < CHAINS; ++k) {
        __builtin_nontemporal_store(v[k], &out4[p[k]]);
    }
}

extern "C" void kernel_launch(void* const* d_in, const int* in_sizes, int n_in,
                              void* d_out, int out_size, void* d_ws, size_t ws_size,
                              hipStream_t stream) {
    const int*   idx = (const int*)d_in[0];
    const fvec4* w4  = (const fvec4*)d_in[1];
    fvec4*       o4  = (fvec4*)d_out;

    const int block = 256;
    const int grid = NTHREADS / block;   // 256 workgroups, 1 per CU
    embedding_gather8_kernel<<<grid, block, 0, stream>>>(idx, w4, o4);
}

// Round 6
// 10.129 us; speedup vs baseline: 1.0724x; 1.0724x over previous
//
#include <hip/hip_runtime.h>

// EmbeddingOnehot: out[n, :] = weights[idx[n], :]  (one_hot @ W == row gather)
// idx: int32 [16384], weights: f32 [32000, 128], out: f32 [16384, 128]
//
// FINAL (= R3, best measured 9.83 us): 4 independent gather chains per thread,
// 512 workgroups. Config sweep {1,4,8 chains} all ~10.4 +/- 0.5 us ->
// launch-overhead floor (ideal traffic ~15 MB ~= 2.5 us; rest is dispatch
// overhead + ramp). Nontemporal stores keep gathered W rows L2-resident.

#define N_TOKENS 16384
#define QUADS_PER_ROW 32                       // 128 floats = 32 x 16B
#define TOTAL_QUADS (N_TOKENS * QUADS_PER_ROW) // 524288
#define NTHREADS (TOTAL_QUADS / 4)             // 131072: 4 quads per thread
#define CHUNK (NTHREADS)

typedef float fvec4 __attribute__((ext_vector_type(4)));

__global__ __launch_bounds__(256) void embedding_gather4_kernel(
    const int* __restrict__ idx,
    const fvec4* __restrict__ w4,
    fvec4* __restrict__ out4)
{
    int j = blockIdx.x * blockDim.x + threadIdx.x;  // 0 .. 131071

    int p0 = j;
    int p1 = j + CHUNK;
    int p2 = j + 2 * CHUNK;
    int p3 = j + 3 * CHUNK;

    // 4 independent idx loads (L1-broadcast within each 32-thread group)
    int r0 = idx[p0 >> 5];
    int r1 = idx[p1 >> 5];
    int r2 = idx[p2 >> 5];
    int r3 = idx[p3 >> 5];

    int q0 = p0 & 31, q1 = p1 & 31, q2 = p2 & 31, q3 = p3 & 31;

    // 4 independent row-gather loads in flight per thread
    fvec4 v0 = w4[r0 * QUADS_PER_ROW + q0];
    fvec4 v1 = w4[r1 * QUADS_PER_ROW + q1];
    fvec4 v2 = w4[r2 * QUADS_PER_ROW + q2];
    fvec4 v3 = w4[r3 * QUADS_PER_ROW + q3];

    __builtin_nontemporal_store(v0, &out4[p0]);
    __builtin_nontemporal_store(v1, &out4[p1]);
    __builtin_nontemporal_store(v2, &out4[p2]);
    __builtin_nontemporal_store(v3, &out4[p3]);
}

extern "C" void kernel_launch(void* const* d_in, const int* in_sizes, int n_in,
                              void* d_out, int out_size, void* d_ws, size_t ws_size,
                              hipStream_t stream) {
    const int*   idx = (const int*)d_in[0];
    const fvec4* w4  = (const fvec4*)d_in[1];
    fvec4*       o4  = (fvec4*)d_out;

    const int block = 256;
    const int grid = NTHREADS / block;   // 512
    embedding_gather4_kernel<<<grid, block, 0, stream>>>(idx, w4, o4);
}